// Round 4
// baseline (275.504 us; speedup 1.0000x reference)
//
#include <hip/hip_runtime.h>

#define Tdim 2048
#define Edim 1024
#define Hdim 16
#define Sdim 64
#define Mdim 4096
#define LN_EPS 1e-5f
#define QKSCALE 0.21233045007200477f  // 1024^-0.25 * sqrt(log2(e))  [log2-domain softmax]

typedef __bf16 bf16x8 __attribute__((ext_vector_type(8)));
typedef float f32x4 __attribute__((ext_vector_type(4)));

__device__ __forceinline__ unsigned short f2bf(float f) {
  union { float f; unsigned int u; } c; c.f = f;
  unsigned int u = c.u;
  return (unsigned short)((u + 0x7FFFu + ((u >> 16) & 1u)) >> 16);
}

__device__ __forceinline__ float exp2fast(float x) {
  float r;
  asm("v_exp_f32 %0, %1" : "=v"(r) : "v"(x));
  return r;
}

// async global->LDS, 16B per lane, lane-contiguous at LDS base (wave-uniform)
__device__ __forceinline__ void gl_lds16(const void* g, void* l) {
  __builtin_amdgcn_global_load_lds(
      (const __attribute__((address_space(1))) void*)g,
      (__attribute__((address_space(3))) void*)l, 16, 0, 0);
}

// pack two fp32 (as bits) -> dword of two bf16 (truncate)
__device__ __forceinline__ unsigned int pk2bf(unsigned int lo, unsigned int hi) {
  return __builtin_amdgcn_perm(hi, lo, 0x07060302u);
}

// ---------------------------------------------------------------------------
// fp32 -> bf16 convert of the three activation matrices
// ---------------------------------------------------------------------------
__global__ __launch_bounds__(256) void cvt_k(
    const float* __restrict__ X0, const float* __restrict__ X1, const float* __restrict__ X2,
    unsigned short* __restrict__ Y0, unsigned short* __restrict__ Y1,
    unsigned short* __restrict__ Y2) {
  const float* X = blockIdx.z == 0 ? X0 : blockIdx.z == 1 ? X1 : X2;
  unsigned short* Y = blockIdx.z == 0 ? Y0 : blockIdx.z == 1 ? Y1 : Y2;
  size_t i = ((size_t)blockIdx.x * 256 + threadIdx.x) * 8;
  uint4 a = *(const uint4*)&X[i];
  uint4 b = *(const uint4*)&X[i + 4];
  uint4 o;
  o.x = pk2bf(a.x, a.y);
  o.y = pk2bf(a.z, a.w);
  o.z = pk2bf(b.x, b.y);
  o.w = pk2bf(b.z, b.w);
  *(uint4*)&Y[i] = o;
}

// ---------------------------------------------------------------------------
// Transpose + convert W [K][N] fp32 -> Wt [N][K] bf16 (4 matrices via grid.z)
// ---------------------------------------------------------------------------
__global__ __launch_bounds__(256) void wconv_k(
    const float* __restrict__ W0, const float* __restrict__ W1,
    const float* __restrict__ W2, const float* __restrict__ W3,
    unsigned short* __restrict__ O0, unsigned short* __restrict__ O1,
    unsigned short* __restrict__ O2, unsigned short* __restrict__ O3) {
  const float* W = blockIdx.z == 0 ? W0 : blockIdx.z == 1 ? W1 : blockIdx.z == 2 ? W2 : W3;
  unsigned short* O = blockIdx.z == 0 ? O0 : blockIdx.z == 1 ? O1 : blockIdx.z == 2 ? O2 : O3;
  __shared__ float tile[32][33];
  int n0 = blockIdx.x * 32, k0 = blockIdx.y * 32;
  int tx = threadIdx.x, ty = threadIdx.y;  // block (32,8)
  for (int yy = ty; yy < 32; yy += 8)
    tile[yy][tx] = W[(size_t)(k0 + yy) * Edim + n0 + tx];
  __syncthreads();
  for (int yy = ty; yy < 32; yy += 8)
    O[(size_t)(n0 + yy) * Edim + k0 + tx] = f2bf(tile[tx][yy]);
}

// ---------------------------------------------------------------------------
// Fused QKV GEMM (pure bf16): 128x128 tile, BK=64, dbuf LDS, gl_lds both ops.
// z<2 : C = X*Wt^T, per-head LN * QKSCALE -> bf16 [B,H,T,S]
// z==2: operands swapped -> C = Wt*X^T = V^T, plain -> bf16 [B,H,S,T]
// Grid: 768 linear, XCD-chunked remap (same-A-panel blocks share an XCD L2).
// ---------------------------------------------------------------------------
__global__ __launch_bounds__(256) void qkv_k(
    const unsigned short* __restrict__ Qa, const unsigned short* __restrict__ Ka,
    const unsigned short* __restrict__ Va,
    const unsigned short* __restrict__ Bq, const unsigned short* __restrict__ Bk,
    const unsigned short* __restrict__ Bv,
    const float* __restrict__ qlnw, const float* __restrict__ qlnb,
    const float* __restrict__ klnw, const float* __restrict__ klnb,
    unsigned short* __restrict__ Oq, unsigned short* __restrict__ Ok,
    unsigned short* __restrict__ Ov) {
  __shared__ unsigned short As[2][128 * 64];
  __shared__ unsigned short Bs[2][128 * 64];
  int f = blockIdx.x;
  int L = (f & 7) * 96 + (f >> 3);
  int bx = L & 7, by = (L >> 3) & 31, z = L >> 8;
  const unsigned short* A = z == 0 ? Qa : z == 1 ? Ka : Va;
  const unsigned short* Bt = z == 0 ? Bq : z == 1 ? Bk : Bv;
  const float* lnw = z == 0 ? qlnw : klnw;
  const float* lnb = z == 0 ? qlnb : klnb;
  unsigned short* obf = z == 0 ? Oq : z == 1 ? Ok : Ov;

  int tid = threadIdx.x, lane = tid & 63, w = tid >> 6;
  int wr = w >> 1, wc = w & 1;
  int lg = lane >> 4, l15 = lane & 15;
  int lr = lane >> 3, ls = lane & 7;
  int m0 = by * 128, n0 = bx * 128;

  f32x4 acc[4][4];
#pragma unroll
  for (int i = 0; i < 4; ++i)
#pragma unroll
    for (int j = 0; j < 4; ++j) acc[i][j] = f32x4{0.f, 0.f, 0.f, 0.f};

  auto stage = [&](int buf, int ks) {
    int k0 = ks * 64;
#pragma unroll
    for (int q = 0; q < 4; ++q) {
      int c = w * 4 + q, r = c * 8 + lr;
      gl_lds16(&A[(size_t)(m0 + r) * Edim + k0 + ((ls ^ (r & 7)) * 8)], &As[buf][c * 512]);
    }
#pragma unroll
    for (int q = 0; q < 4; ++q) {
      int c = w * 4 + q, r = c * 8 + lr;
      gl_lds16(&Bt[(size_t)(n0 + r) * Edim + k0 + ((ls ^ (r & 7)) * 8)], &Bs[buf][c * 512]);
    }
  };

  stage(0, 0);
  for (int ks = 0; ks < 16; ++ks) {
    int cur = ks & 1;
    __syncthreads();
    if (ks + 1 < 16) stage(cur ^ 1, ks + 1);
    const unsigned short* pA = (z == 2) ? &Bs[cur][0] : &As[cur][0];
    const unsigned short* pB = (z == 2) ? &As[cur][0] : &Bs[cur][0];
    __builtin_amdgcn_s_setprio(1);
#pragma unroll
    for (int kx = 0; kx < 2; ++kx) {
      bf16x8 a[4], bb[4];
#pragma unroll
      for (int i = 0; i < 4; ++i) {
        int r = wr * 64 + i * 16 + l15;
        a[i] = *(const bf16x8*)&pA[r * 64 + (((kx * 4 + lg) ^ (r & 7)) * 8)];
      }
#pragma unroll
      for (int j = 0; j < 4; ++j) {
        int r = wc * 64 + j * 16 + l15;
        bb[j] = *(const bf16x8*)&pB[r * 64 + (((kx * 4 + lg) ^ (r & 7)) * 8)];
      }
#pragma unroll
      for (int i = 0; i < 4; ++i)
#pragma unroll
        for (int j = 0; j < 4; ++j)
          acc[i][j] = __builtin_amdgcn_mfma_f32_16x16x32_bf16(a[i], bb[j], acc[i][j], 0, 0, 0);
    }
    __builtin_amdgcn_s_setprio(0);
  }

  if (z < 2) {
    int mb = m0 + wr * 64;
    int h = (n0 >> 6) + wc;  // wave's 64 cols == one head
#pragma unroll
    for (int i = 0; i < 4; ++i) {
#pragma unroll
      for (int r = 0; r < 4; ++r) {
        float xv[4];
#pragma unroll
        for (int j = 0; j < 4; ++j) xv[j] = acc[i][j][r];
        float sum = xv[0] + xv[1] + xv[2] + xv[3];
        float sq = xv[0] * xv[0] + xv[1] * xv[1] + xv[2] * xv[2] + xv[3] * xv[3];
#pragma unroll
        for (int off = 1; off < 16; off <<= 1) {
          sum += __shfl_xor(sum, off);
          sq += __shfl_xor(sq, off);
        }
        float mean = sum * (1.f / 64.f);
        float var = sq * (1.f / 64.f) - mean * mean;
        float rstd = rsqrtf(var + LN_EPS);
        int m = mb + i * 16 + (lg << 2) + r;
        int bb2 = m >> 11, tt = m & 2047;
        size_t base = ((size_t)(bb2 * Hdim + h) * Tdim + tt) * Sdim;
#pragma unroll
        for (int j = 0; j < 4; ++j) {
          int s = j * 16 + l15;
          float ov = ((xv[j] - mean) * rstd * lnw[s] + lnb[s]) * QKSCALE;
          obf[base + s] = f2bf(ov);
        }
      }
    }
  } else {
    // C = V^T : row = head-col (n0-block, via wr/i/lg/r), col = token (m0-block)
#pragma unroll
    for (int i = 0; i < 4; ++i)
#pragma unroll
      for (int r = 0; r < 4; ++r) {
        int hc = n0 + wr * 64 + i * 16 + (lg << 2) + r;
        int h = hc >> 6, s = hc & 63;
#pragma unroll
        for (int j = 0; j < 4; ++j) {
          int tk = m0 + wc * 64 + j * 16 + l15;
          int bb2 = tk >> 11, tt = tk & 2047;
          obf[(((size_t)(bb2 * Hdim + h) * Sdim + s)) * Tdim + tt] = f2bf(acc[i][j][r]);
        }
      }
  }
}

// ---------------------------------------------------------------------------
// Out-projection GEMM: Y = Ob(bf16) * Wto^T + bo -> fp32. 128x64 tile, BK=64.
// ---------------------------------------------------------------------------
__global__ __launch_bounds__(256) void gemmo_k(
    const unsigned short* __restrict__ A, const unsigned short* __restrict__ Bt,
    const float* __restrict__ bias, float* __restrict__ ofp) {
  __shared__ unsigned short As[2][128 * 64];
  __shared__ unsigned short Bs[2][64 * 64];
  int f = blockIdx.x;
  int L = (f & 7) * 64 + (f >> 3);
  int bx = L & 15, by = L >> 4;
  int tid = threadIdx.x, lane = tid & 63, w = tid >> 6;
  int wr = w >> 1, wc = w & 1;
  int lg = lane >> 4, l15 = lane & 15;
  int lr = lane >> 3, ls = lane & 7;
  int m0 = by * 128, n0 = bx * 64;

  f32x4 acc[4][2];
#pragma unroll
  for (int i = 0; i < 4; ++i)
#pragma unroll
    for (int j = 0; j < 2; ++j) acc[i][j] = f32x4{0.f, 0.f, 0.f, 0.f};

  auto stage = [&](int buf, int ks) {
    int k0 = ks * 64;
#pragma unroll
    for (int q = 0; q < 4; ++q) {
      int c = w * 4 + q, r = c * 8 + lr;
      gl_lds16(&A[(size_t)(m0 + r) * Edim + k0 + ((ls ^ (r & 7)) * 8)], &As[buf][c * 512]);
    }
#pragma unroll
    for (int q = 0; q < 2; ++q) {
      int c = w * 2 + q, r = c * 8 + lr;
      gl_lds16(&Bt[(size_t)(n0 + r) * Edim + k0 + ((ls ^ (r & 7)) * 8)], &Bs[buf][c * 512]);
    }
  };

  stage(0, 0);
  for (int ks = 0; ks < 16; ++ks) {
    int cur = ks & 1;
    __syncthreads();
    if (ks + 1 < 16) stage(cur ^ 1, ks + 1);
    __builtin_amdgcn_s_setprio(1);
#pragma unroll
    for (int kx = 0; kx < 2; ++kx) {
      bf16x8 a[4], bb[2];
#pragma unroll
      for (int i = 0; i < 4; ++i) {
        int r = wr * 64 + i * 16 + l15;
        a[i] = *(const bf16x8*)&As[cur][r * 64 + (((kx * 4 + lg) ^ (r & 7)) * 8)];
      }
#pragma unroll
      for (int j = 0; j < 2; ++j) {
        int r = wc * 32 + j * 16 + l15;
        bb[j] = *(const bf16x8*)&Bs[cur][r * 64 + (((kx * 4 + lg) ^ (r & 7)) * 8)];
      }
#pragma unroll
      for (int i = 0; i < 4; ++i)
#pragma unroll
        for (int j = 0; j < 2; ++j)
          acc[i][j] = __builtin_amdgcn_mfma_f32_16x16x32_bf16(a[i], bb[j], acc[i][j], 0, 0, 0);
    }
    __builtin_amdgcn_s_setprio(0);
  }

  int mb = m0 + wr * 64, nb = n0 + wc * 32;
#pragma unroll
  for (int i = 0; i < 4; ++i)
#pragma unroll
    for (int r = 0; r < 4; ++r) {
      int m = mb + i * 16 + (lg << 2) + r;
#pragma unroll
      for (int j = 0; j < 2; ++j) {
        int n = nb + j * 16 + l15;
        ofp[(size_t)m * Edim + n] = acc[i][j][r] + bias[n];
      }
    }
}

// ---------------------------------------------------------------------------
// Flash attention, log2-domain, 2-deep score pipeline.
// 4 waves x 16 q-rows (QBLK=64), KVBLK=64. K triple-buffered, V double-
// buffered, both via gl_lds (V pre-transposed to [B,H,S,T] by qkv_k).
// Joint running-max shared across a lane-group's 4 rows; deferred l-sum.
// Pair-fold: block handles q-segments x and 31-x (33 tiles each).
// ---------------------------------------------------------------------------
__global__ __launch_bounds__(256) void flash_k(
    const unsigned short* __restrict__ Qn, const unsigned short* __restrict__ Kn,
    const unsigned short* __restrict__ Vb, unsigned short* __restrict__ Ob) {
  __shared__ unsigned short Qs[4096];
  __shared__ unsigned short Ks[3][4096];
  __shared__ unsigned short Vt[2][4096];
  __shared__ unsigned short Ps[4][1024];

  int wid0 = blockIdx.y * gridDim.x + blockIdx.x;
  int wid = (wid0 & 7) * 64 + (wid0 >> 3);  // same-bh blocks share an XCD
  int x = wid & 15, bh = wid >> 4;

  int tid = threadIdx.x, lane = tid & 63, w = tid >> 6;
  int lg = lane >> 4, l15 = lane & 15;
  int lr = lane >> 3, ls = lane & 7;
  const unsigned short* Kg = Kn + (size_t)bh * Tdim * Sdim;       // [t][s]
  const unsigned short* Vg = Vb + (size_t)bh * Sdim * Tdim;       // [s][t]
  int b = bh >> 4, h = bh & 15;

  auto stageK = [&](int tt, int kb) {
    const unsigned short* src = Kg + (size_t)tt * 64 * 64;
#pragma unroll
    for (int q = 0; q < 2; ++q) {
      int c = w * 2 + q, r = c * 8 + lr;
      gl_lds16(&src[r * 64 + ((ls ^ (r & 7)) * 8)], &Ks[kb][c * 512]);
    }
  };
  auto stageV = [&](int tt, int vb) {
    const unsigned short* src = Vg + tt * 64;  // rows = s (stride Tdim), cols = kv
#pragma unroll
    for (int q = 0; q < 2; ++q) {
      int c = w * 2 + q, r = c * 8 + lr;
      gl_lds16(&src[(size_t)r * Tdim + ((ls ^ (r & 7)) * 8)], &Vt[vb][c * 512]);
    }
  };

  for (int ph = 0; ph < 2; ++ph) {
    int qseg = ph ? (31 - x) : x;
    int nt = qseg + 1;
    const unsigned short* Qg = Qn + ((size_t)bh * Tdim + (size_t)qseg * 64) * Sdim;

    // prologue staging (async)
#pragma unroll
    for (int q = 0; q < 2; ++q) {
      int c = w * 2 + q, r = c * 8 + lr;
      gl_lds16(&Qg[r * 64 + ((ls ^ (r & 7)) * 8)], &Qs[c * 512]);
    }
    stageK(0, 0);
    if (nt > 1) stageK(1, 1);
    stageV(0, 0);

    float mrun = -1e30f;
    float lrun[4] = {0.f, 0.f, 0.f, 0.f};
    f32x4 o[4];
#pragma unroll
    for (int js = 0; js < 4; ++js) o[js] = f32x4{0.f, 0.f, 0.f, 0.f};

    __syncthreads();

    bf16x8 aq[2];
    {
      int rq = w * 16 + l15;
      aq[0] = *(const bf16x8*)&Qs[rq * 64 + ((lg ^ (rq & 7)) * 8)];
      aq[1] = *(const bf16x8*)&Qs[rq * 64 + (((4 + lg) ^ (rq & 7)) * 8)];
    }

    auto QK = [&](f32x4(&dst)[4], int tt) {
      const unsigned short* Kc = &Ks[tt % 3][0];
#pragma unroll
      for (int j = 0; j < 4; ++j) dst[j] = f32x4{0.f, 0.f, 0.f, 0.f};
      __builtin_amdgcn_s_setprio(1);
#pragma unroll
      for (int kx = 0; kx < 2; ++kx) {
#pragma unroll
        for (int j = 0; j < 4; ++j) {
          int rk = j * 16 + l15;
          bf16x8 bk = *(const bf16x8*)&Kc[rk * 64 + (((kx * 4 + lg) ^ (rk & 7)) * 8)];
          dst[j] = __builtin_amdgcn_mfma_f32_16x16x32_bf16(aq[kx], bk, dst[j], 0, 0, 0);
        }
      }
      __builtin_amdgcn_s_setprio(0);
    };

    auto SMPV = [&](f32x4(&cur)[4], int t) {
      if (t == nt - 1) {  // causal diagonal tile
#pragma unroll
        for (int j = 0; j < 4; ++j)
#pragma unroll
          for (int rr = 0; rr < 4; ++rr)
            if (j * 16 + l15 > w * 16 + (lg << 2) + rr) cur[j][rr] = -1e30f;
      }
      // joint max over the lane-group's 4 rows (valid shared reference max)
      float mx = -3e38f;
#pragma unroll
      for (int j = 0; j < 4; ++j)
#pragma unroll
        for (int rr = 0; rr < 4; ++rr) mx = fmaxf(mx, cur[j][rr]);
#pragma unroll
      for (int off = 1; off < 16; off <<= 1) mx = fmaxf(mx, __shfl_xor(mx, off));
      if (__any(mx > mrun + 8.f)) {  // defer-max: rescale only on real growth
        float mnew = fmaxf(mrun, mx);
        float alpha = exp2fast(mrun - mnew);
        mrun = mnew;
#pragma unroll
        for (int rr = 0; rr < 4; ++rr) lrun[rr] *= alpha;
#pragma unroll
        for (int js = 0; js < 4; ++js) o[js] *= alpha;
      }
      unsigned short* Pw = &Ps[w][0];
#pragma unroll
      for (int j = 0; j < 4; ++j) {
        int og = 2 * j + (l15 >> 3);
#pragma unroll
        for (int rr = 0; rr < 4; ++rr) {
          float p = exp2fast(cur[j][rr] - mrun);
          lrun[rr] += p;
          union { float f; unsigned int u; } cu;
          cu.f = p;
          int qr = (lg << 2) + rr;
          Pw[qr * 64 + ((og ^ (qr & 7)) * 8) + (l15 & 7)] = (unsigned short)(cu.u >> 16);
        }
      }
      const unsigned short* Vc = &Vt[t & 1][0];
      __builtin_amdgcn_s_setprio(1);
#pragma unroll
      for (int kx = 0; kx < 2; ++kx) {
        bf16x8 ap = *(const bf16x8*)&Pw[l15 * 64 + (((kx * 4 + lg) ^ (l15 & 7)) * 8)];
#pragma unroll
        for (int js = 0; js < 4; ++js) {
          int rv = js * 16 + l15;
          bf16x8 bv = *(const bf16x8*)&Vc[rv * 64 + (((kx * 4 + lg) ^ (rv & 7)) * 8)];
          o[js] = __builtin_amdgcn_mfma_f32_16x16x32_bf16(ap, bv, o[js], 0, 0, 0);
        }
      }
      __builtin_amdgcn_s_setprio(0);
    };

    f32x4 sA[4], sB[4];
    QK(sA, 0);
    for (int t = 0; t < nt; ++t) {
      if (t + 2 < nt) stageK(t + 2, (t + 2) % 3);   // async, lands by next barrier
      if (t + 1 < nt) stageV(t + 1, (t + 1) & 1);
      if (t + 1 < nt) {                              // score pipeline: QK(t+1) first
        if (t & 1) QK(sA, t + 1); else QK(sB, t + 1);
      }
      if (t & 1) SMPV(sB, t); else SMPV(sA, t);      // softmax+PV of tile t
      __syncthreads();
    }

    // epilogue: reduce deferred l, normalize, store
#pragma unroll
    for (int rr = 0; rr < 4; ++rr) {
      float l = lrun[rr];
#pragma unroll
      for (int off = 1; off < 16; off <<= 1) l += __shfl_xor(l, off);
      float inv = 1.f / l;
      int tg = qseg * 64 + w * 16 + (lg << 2) + rr;
      size_t base = ((size_t)b * Tdim + tg) * Edim + h * 64;
#pragma unroll
      for (int js = 0; js < 4; ++js) Ob[base + js * 16 + l15] = f2bf(o[js][rr] * inv);
    }
  }
}

// ---------------------------------------------------------------------------
extern "C" void kernel_launch(void* const* d_in, const int* in_sizes, int n_in,
                              void* d_out, int out_size, void* d_ws, size_t ws_size,
                              hipStream_t stream) {
  const float* queries = (const float*)d_in[0];
  const float* keys    = (const float*)d_in[1];
  const float* values  = (const float*)d_in[2];
  const float* Wq = (const float*)d_in[3];
  const float* Wk = (const float*)d_in[4];
  const float* Wv = (const float*)d_in[5];
  const float* Wo = (const float*)d_in[6];
  const float* bo = (const float*)d_in[7];
  const float* qlnw = (const float*)d_in[8];
  const float* qlnb = (const float*)d_in[9];
  const float* klnw = (const float*)d_in[10];
  const float* klnb = (const float*)d_in[11];
  float* out = (float*)d_out;

  unsigned short* Wtq = (unsigned short*)d_ws;          // 4 x 2MB
  unsigned short* Wtk = Wtq + 1024 * 1024;
  unsigned short* Wtv = Wtk + 1024 * 1024;
  unsigned short* Wto = Wtv + 1024 * 1024;
  unsigned short* Qn  = Wto + 1024 * 1024;              // [B,H,T,S]
  unsigned short* Kn  = Qn + (size_t)Mdim * Edim;       // [B,H,T,S]
  unsigned short* Vb  = Kn + (size_t)Mdim * Edim;       // [B,H,S,T] (transposed)
  unsigned short* Qa  = Vb + (size_t)Mdim * Edim;       // bf16 activations
  unsigned short* Ka  = Qa + (size_t)Mdim * Edim;
  unsigned short* Va  = Ka + (size_t)Mdim * Edim;
  unsigned short* Ob  = Qa;                             // alias: Qa dead after qkv_k

  cvt_k<<<dim3(2048, 1, 3), 256, 0, stream>>>(queries, keys, values, Qa, Ka, Va);
  wconv_k<<<dim3(32, 32, 4), dim3(32, 8), 0, stream>>>(Wq, Wk, Wv, Wo, Wtq, Wtk, Wtv, Wto);
  qkv_k<<<768, 256, 0, stream>>>(Qa, Ka, Va, Wtq, Wtk, Wtv,
                                 qlnw, qlnb, klnw, klnb, Qn, Kn, Vb);
  flash_k<<<dim3(16, 32), 256, 0, stream>>>(Qn, Kn, Vb, Ob);
  gemmo_k<<<512, 256, 0, stream>>>(Ob, Wto, bo, out);
}

// Round 5
// 228.514 us; speedup vs baseline: 1.2056x; 1.2056x over previous
//
#include <hip/hip_runtime.h>

#define Tdim 2048
#define Edim 1024
#define Hdim 16
#define Sdim 64
#define Mdim 4096
#define LN_EPS 1e-5f
#define QKSCALE 0.21233045007200477f  // 1024^-0.25 * sqrt(log2(e))  [log2-domain softmax]

typedef __bf16 bf16x8 __attribute__((ext_vector_type(8)));
typedef float f32x4 __attribute__((ext_vector_type(4)));

__device__ __forceinline__ unsigned short f2bf(float f) {
  union { float f; unsigned int u; } c; c.f = f;
  unsigned int u = c.u;
  return (unsigned short)((u + 0x7FFFu + ((u >> 16) & 1u)) >> 16);
}

__device__ __forceinline__ float exp2fast(float x) {
  float r;
  asm("v_exp_f32 %0, %1" : "=v"(r) : "v"(x));
  return r;
}

// async global->LDS, 16B per lane, lane-contiguous at LDS base (wave-uniform)
__device__ __forceinline__ void gl_lds16(const void* g, void* l) {
  __builtin_amdgcn_global_load_lds(
      (const __attribute__((address_space(1))) void*)g,
      (__attribute__((address_space(3))) void*)l, 16, 0, 0);
}

// pack two fp32 (as bits) -> dword of two bf16 (truncate)
__device__ __forceinline__ unsigned int pk2bf(unsigned int lo, unsigned int hi) {
  return __builtin_amdgcn_perm(hi, lo, 0x07060302u);
}

// ---------------------------------------------------------------------------
// fp32 -> bf16 convert of the three activation matrices
// ---------------------------------------------------------------------------
__global__ __launch_bounds__(256) void cvt_k(
    const float* __restrict__ X0, const float* __restrict__ X1, const float* __restrict__ X2,
    unsigned short* __restrict__ Y0, unsigned short* __restrict__ Y1,
    unsigned short* __restrict__ Y2) {
  const float* X = blockIdx.z == 0 ? X0 : blockIdx.z == 1 ? X1 : X2;
  unsigned short* Y = blockIdx.z == 0 ? Y0 : blockIdx.z == 1 ? Y1 : Y2;
  size_t i = ((size_t)blockIdx.x * 256 + threadIdx.x) * 8;
  uint4 a = *(const uint4*)&X[i];
  uint4 b = *(const uint4*)&X[i + 4];
  uint4 o;
  o.x = pk2bf(a.x, a.y);
  o.y = pk2bf(a.z, a.w);
  o.z = pk2bf(b.x, b.y);
  o.w = pk2bf(b.z, b.w);
  *(uint4*)&Y[i] = o;
}

// ---------------------------------------------------------------------------
// Transpose + convert W [K][N] fp32 -> Wt [N][K] bf16 (4 matrices via grid.z)
// ---------------------------------------------------------------------------
__global__ __launch_bounds__(256) void wconv_k(
    const float* __restrict__ W0, const float* __restrict__ W1,
    const float* __restrict__ W2, const float* __restrict__ W3,
    unsigned short* __restrict__ O0, unsigned short* __restrict__ O1,
    unsigned short* __restrict__ O2, unsigned short* __restrict__ O3) {
  const float* W = blockIdx.z == 0 ? W0 : blockIdx.z == 1 ? W1 : blockIdx.z == 2 ? W2 : W3;
  unsigned short* O = blockIdx.z == 0 ? O0 : blockIdx.z == 1 ? O1 : blockIdx.z == 2 ? O2 : O3;
  __shared__ float tile[32][33];
  int n0 = blockIdx.x * 32, k0 = blockIdx.y * 32;
  int tx = threadIdx.x, ty = threadIdx.y;  // block (32,8)
  for (int yy = ty; yy < 32; yy += 8)
    tile[yy][tx] = W[(size_t)(k0 + yy) * Edim + n0 + tx];
  __syncthreads();
  for (int yy = ty; yy < 32; yy += 8)
    O[(size_t)(n0 + yy) * Edim + k0 + tx] = f2bf(tile[tx][yy]);
}

// ---------------------------------------------------------------------------
// Fused QKV GEMM (pure bf16): 128x128 tile, BK=64, dbuf LDS, gl_lds both ops.
// z<2 : C = X*Wt^T, per-head LN * QKSCALE -> bf16 [B,H,T,S]
// z==2: operands swapped -> C = Wt*X^T = V^T, plain -> bf16 [B,H,S,T]
// Grid: 768 linear, XCD-chunked remap (same-A-panel blocks share an XCD L2).
// ---------------------------------------------------------------------------
__global__ __launch_bounds__(256) void qkv_k(
    const unsigned short* __restrict__ Qa, const unsigned short* __restrict__ Ka,
    const unsigned short* __restrict__ Va,
    const unsigned short* __restrict__ Bq, const unsigned short* __restrict__ Bk,
    const unsigned short* __restrict__ Bv,
    const float* __restrict__ qlnw, const float* __restrict__ qlnb,
    const float* __restrict__ klnw, const float* __restrict__ klnb,
    unsigned short* __restrict__ Oq, unsigned short* __restrict__ Ok,
    unsigned short* __restrict__ Ov) {
  __shared__ unsigned short As[2][128 * 64];
  __shared__ unsigned short Bs[2][128 * 64];
  int f = blockIdx.x;
  int L = (f & 7) * 96 + (f >> 3);
  int bx = L & 7, by = (L >> 3) & 31, z = L >> 8;
  const unsigned short* A = z == 0 ? Qa : z == 1 ? Ka : Va;
  const unsigned short* Bt = z == 0 ? Bq : z == 1 ? Bk : Bv;
  const float* lnw = z == 0 ? qlnw : klnw;
  const float* lnb = z == 0 ? qlnb : klnb;
  unsigned short* obf = z == 0 ? Oq : z == 1 ? Ok : Ov;

  int tid = threadIdx.x, lane = tid & 63, w = tid >> 6;
  int wr = w >> 1, wc = w & 1;
  int lg = lane >> 4, l15 = lane & 15;
  int lr = lane >> 3, ls = lane & 7;
  int m0 = by * 128, n0 = bx * 128;

  f32x4 acc[4][4];
#pragma unroll
  for (int i = 0; i < 4; ++i)
#pragma unroll
    for (int j = 0; j < 4; ++j) acc[i][j] = f32x4{0.f, 0.f, 0.f, 0.f};

  auto stage = [&](int buf, int ks) {
    int k0 = ks * 64;
#pragma unroll
    for (int q = 0; q < 4; ++q) {
      int c = w * 4 + q, r = c * 8 + lr;
      gl_lds16(&A[(size_t)(m0 + r) * Edim + k0 + ((ls ^ (r & 7)) * 8)], &As[buf][c * 512]);
    }
#pragma unroll
    for (int q = 0; q < 4; ++q) {
      int c = w * 4 + q, r = c * 8 + lr;
      gl_lds16(&Bt[(size_t)(n0 + r) * Edim + k0 + ((ls ^ (r & 7)) * 8)], &Bs[buf][c * 512]);
    }
  };

  stage(0, 0);
  for (int ks = 0; ks < 16; ++ks) {
    int cur = ks & 1;
    __syncthreads();
    if (ks + 1 < 16) stage(cur ^ 1, ks + 1);
    const unsigned short* pA = (z == 2) ? &Bs[cur][0] : &As[cur][0];
    const unsigned short* pB = (z == 2) ? &As[cur][0] : &Bs[cur][0];
    __builtin_amdgcn_s_setprio(1);
#pragma unroll
    for (int kx = 0; kx < 2; ++kx) {
      bf16x8 a[4], bb[4];
#pragma unroll
      for (int i = 0; i < 4; ++i) {
        int r = wr * 64 + i * 16 + l15;
        a[i] = *(const bf16x8*)&pA[r * 64 + (((kx * 4 + lg) ^ (r & 7)) * 8)];
      }
#pragma unroll
      for (int j = 0; j < 4; ++j) {
        int r = wc * 64 + j * 16 + l15;
        bb[j] = *(const bf16x8*)&pB[r * 64 + (((kx * 4 + lg) ^ (r & 7)) * 8)];
      }
#pragma unroll
      for (int i = 0; i < 4; ++i)
#pragma unroll
        for (int j = 0; j < 4; ++j)
          acc[i][j] = __builtin_amdgcn_mfma_f32_16x16x32_bf16(a[i], bb[j], acc[i][j], 0, 0, 0);
    }
    __builtin_amdgcn_s_setprio(0);
  }

  if (z < 2) {
    int mb = m0 + wr * 64;
    int h = (n0 >> 6) + wc;  // wave's 64 cols == one head
#pragma unroll
    for (int i = 0; i < 4; ++i) {
#pragma unroll
      for (int r = 0; r < 4; ++r) {
        float xv[4];
#pragma unroll
        for (int j = 0; j < 4; ++j) xv[j] = acc[i][j][r];
        float sum = xv[0] + xv[1] + xv[2] + xv[3];
        float sq = xv[0] * xv[0] + xv[1] * xv[1] + xv[2] * xv[2] + xv[3] * xv[3];
#pragma unroll
        for (int off = 1; off < 16; off <<= 1) {
          sum += __shfl_xor(sum, off);
          sq += __shfl_xor(sq, off);
        }
        float mean = sum * (1.f / 64.f);
        float var = sq * (1.f / 64.f) - mean * mean;
        float rstd = rsqrtf(var + LN_EPS);
        int m = mb + i * 16 + (lg << 2) + r;
        int bb2 = m >> 11, tt = m & 2047;
        size_t base = ((size_t)(bb2 * Hdim + h) * Tdim + tt) * Sdim;
#pragma unroll
        for (int j = 0; j < 4; ++j) {
          int s = j * 16 + l15;
          float ov = ((xv[j] - mean) * rstd * lnw[s] + lnb[s]) * QKSCALE;
          obf[base + s] = f2bf(ov);
        }
      }
    }
  } else {
    // C = V^T : row = head-col (n0-block, via wr/i/lg/r), col = token (m0-block)
#pragma unroll
    for (int i = 0; i < 4; ++i)
#pragma unroll
      for (int r = 0; r < 4; ++r) {
        int hc = n0 + wr * 64 + i * 16 + (lg << 2) + r;
        int h = hc >> 6, s = hc & 63;
#pragma unroll
        for (int j = 0; j < 4; ++j) {
          int tk = m0 + wc * 64 + j * 16 + l15;
          int bb2 = tk >> 11, tt = tk & 2047;
          obf[(((size_t)(bb2 * Hdim + h) * Sdim + s)) * Tdim + tt] = f2bf(acc[i][j][r]);
        }
      }
  }
}

// ---------------------------------------------------------------------------
// Out-projection GEMM: Y = Ob(bf16) * Wto^T + bo -> fp32. 128x64 tile, BK=64.
// ---------------------------------------------------------------------------
__global__ __launch_bounds__(256) void gemmo_k(
    const unsigned short* __restrict__ A, const unsigned short* __restrict__ Bt,
    const float* __restrict__ bias, float* __restrict__ ofp) {
  __shared__ unsigned short As[2][128 * 64];
  __shared__ unsigned short Bs[2][64 * 64];
  int f = blockIdx.x;
  int L = (f & 7) * 64 + (f >> 3);
  int bx = L & 15, by = L >> 4;
  int tid = threadIdx.x, lane = tid & 63, w = tid >> 6;
  int wr = w >> 1, wc = w & 1;
  int lg = lane >> 4, l15 = lane & 15;
  int lr = lane >> 3, ls = lane & 7;
  int m0 = by * 128, n0 = bx * 64;

  f32x4 acc[4][2];
#pragma unroll
  for (int i = 0; i < 4; ++i)
#pragma unroll
    for (int j = 0; j < 2; ++j) acc[i][j] = f32x4{0.f, 0.f, 0.f, 0.f};

  auto stage = [&](int buf, int ks) {
    int k0 = ks * 64;
#pragma unroll
    for (int q = 0; q < 4; ++q) {
      int c = w * 4 + q, r = c * 8 + lr;
      gl_lds16(&A[(size_t)(m0 + r) * Edim + k0 + ((ls ^ (r & 7)) * 8)], &As[buf][c * 512]);
    }
#pragma unroll
    for (int q = 0; q < 2; ++q) {
      int c = w * 2 + q, r = c * 8 + lr;
      gl_lds16(&Bt[(size_t)(n0 + r) * Edim + k0 + ((ls ^ (r & 7)) * 8)], &Bs[buf][c * 512]);
    }
  };

  stage(0, 0);
  for (int ks = 0; ks < 16; ++ks) {
    int cur = ks & 1;
    __syncthreads();
    if (ks + 1 < 16) stage(cur ^ 1, ks + 1);
    __builtin_amdgcn_s_setprio(1);
#pragma unroll
    for (int kx = 0; kx < 2; ++kx) {
      bf16x8 a[4], bb[2];
#pragma unroll
      for (int i = 0; i < 4; ++i) {
        int r = wr * 64 + i * 16 + l15;
        a[i] = *(const bf16x8*)&As[cur][r * 64 + (((kx * 4 + lg) ^ (r & 7)) * 8)];
      }
#pragma unroll
      for (int j = 0; j < 2; ++j) {
        int r = wc * 32 + j * 16 + l15;
        bb[j] = *(const bf16x8*)&Bs[cur][r * 64 + (((kx * 4 + lg) ^ (r & 7)) * 8)];
      }
#pragma unroll
      for (int i = 0; i < 4; ++i)
#pragma unroll
        for (int j = 0; j < 2; ++j)
          acc[i][j] = __builtin_amdgcn_mfma_f32_16x16x32_bf16(a[i], bb[j], acc[i][j], 0, 0, 0);
    }
    __builtin_amdgcn_s_setprio(0);
  }

  int mb = m0 + wr * 64, nb = n0 + wc * 32;
#pragma unroll
  for (int i = 0; i < 4; ++i)
#pragma unroll
    for (int r = 0; r < 4; ++r) {
      int m = mb + i * 16 + (lg << 2) + r;
#pragma unroll
      for (int j = 0; j < 2; ++j) {
        int n = nb + j * 16 + l15;
        ofp[(size_t)m * Edim + n] = acc[i][j][r] + bias[n];
      }
    }
}

// ---------------------------------------------------------------------------
// Flash attention, log2-domain. 4 waves x 16 q-rows (QBLK=64), KVBLK=64.
// Grid: 1024 blocks, one q-segment each, dispatched longest-first for greedy
// balance; bh = 4*(wid&7) + (idx&3) keeps each XCD's K/V set at 2MB (L2-fit).
// K,V double-buffered via gl_lds (V pre-transposed to [B,H,S,T] by qkv_k).
// Joint running-max per lane-group; deferred l-sum; one barrier per tile.
// LDS 48KB -> 3 blocks/CU resident.
// ---------------------------------------------------------------------------
__global__ __launch_bounds__(256) void flash_k(
    const unsigned short* __restrict__ Qn, const unsigned short* __restrict__ Kn,
    const unsigned short* __restrict__ Vb, unsigned short* __restrict__ Ob) {
  __shared__ unsigned short Qs[4096];
  __shared__ unsigned short Ks[2][4096];
  __shared__ unsigned short Vt[2][4096];
  __shared__ unsigned short Ps[4][1024];

  int wid0 = blockIdx.x;
  int idx = wid0 >> 3;
  int bh = (wid0 & 7) * 4 + (idx & 3);   // 4 heads per XCD -> K/V 2MB in L2
  int qseg = 31 - (idx >> 2);            // longest blocks dispatch first
  int nt = qseg + 1;

  int tid = threadIdx.x, lane = tid & 63, w = tid >> 6;
  int lg = lane >> 4, l15 = lane & 15;
  int lr = lane >> 3, ls = lane & 7;
  const unsigned short* Qg = Qn + ((size_t)bh * Tdim + (size_t)qseg * 64) * Sdim;
  const unsigned short* Kg = Kn + (size_t)bh * Tdim * Sdim;  // [t][s]
  const unsigned short* Vg = Vb + (size_t)bh * Sdim * Tdim;  // [s][t]
  int b = bh >> 4, h = bh & 15;

  auto stageK = [&](int tt, int kb) {
    const unsigned short* src = Kg + (size_t)tt * 64 * 64;
#pragma unroll
    for (int q = 0; q < 2; ++q) {
      int c = w * 2 + q, r = c * 8 + lr;
      gl_lds16(&src[r * 64 + ((ls ^ (r & 7)) * 8)], &Ks[kb][c * 512]);
    }
  };
  auto stageV = [&](int tt, int vb) {
    const unsigned short* src = Vg + tt * 64;  // rows = s (stride Tdim), cols = kv
#pragma unroll
    for (int q = 0; q < 2; ++q) {
      int c = w * 2 + q, r = c * 8 + lr;
      gl_lds16(&src[(size_t)r * Tdim + ((ls ^ (r & 7)) * 8)], &Vt[vb][c * 512]);
    }
  };

  // prologue staging (async)
#pragma unroll
  for (int q = 0; q < 2; ++q) {
    int c = w * 2 + q, r = c * 8 + lr;
    gl_lds16(&Qg[r * 64 + ((ls ^ (r & 7)) * 8)], &Qs[c * 512]);
  }
  stageK(0, 0);
  stageV(0, 0);

  float mrun = -1e30f;
  float lrun[4] = {0.f, 0.f, 0.f, 0.f};
  f32x4 o[4];
#pragma unroll
  for (int js = 0; js < 4; ++js) o[js] = f32x4{0.f, 0.f, 0.f, 0.f};

  __syncthreads();

  bf16x8 aq[2];
  {
    int rq = w * 16 + l15;
    aq[0] = *(const bf16x8*)&Qs[rq * 64 + ((lg ^ (rq & 7)) * 8)];
    aq[1] = *(const bf16x8*)&Qs[rq * 64 + (((4 + lg) ^ (rq & 7)) * 8)];
  }

  for (int t = 0; t < nt; ++t) {
    int cur = t & 1;
    if (t + 1 < nt) {  // async prefetch; drained by end-of-iter barrier
      stageK(t + 1, cur ^ 1);
      stageV(t + 1, cur ^ 1);
    }
    // S = Q K^T (log2-domain scores; scale folded into Q,K)
    f32x4 sf[4];
#pragma unroll
    for (int j = 0; j < 4; ++j) sf[j] = f32x4{0.f, 0.f, 0.f, 0.f};
    const unsigned short* Kc = &Ks[cur][0];
    __builtin_amdgcn_s_setprio(1);
#pragma unroll
    for (int kx = 0; kx < 2; ++kx) {
#pragma unroll
      for (int j = 0; j < 4; ++j) {
        int rk = j * 16 + l15;
        bf16x8 bk = *(const bf16x8*)&Kc[rk * 64 + (((kx * 4 + lg) ^ (rk & 7)) * 8)];
        sf[j] = __builtin_amdgcn_mfma_f32_16x16x32_bf16(aq[kx], bk, sf[j], 0, 0, 0);
      }
    }
    __builtin_amdgcn_s_setprio(0);
    if (t == qseg) {  // causal diagonal tile
#pragma unroll
      for (int j = 0; j < 4; ++j)
#pragma unroll
        for (int rr = 0; rr < 4; ++rr)
          if (j * 16 + l15 > w * 16 + (lg << 2) + rr) sf[j][rr] = -1e30f;
    }
    // joint max over lane-group's 4 rows (any shared reference max is valid)
    float mx = -3e38f;
#pragma unroll
    for (int j = 0; j < 4; ++j)
#pragma unroll
      for (int rr = 0; rr < 4; ++rr) mx = fmaxf(mx, sf[j][rr]);
#pragma unroll
    for (int off = 1; off < 16; off <<= 1) mx = fmaxf(mx, __shfl_xor(mx, off));
    if (__any(mx > mrun + 8.f)) {  // defer-max: rescale only on real growth
      float mnew = fmaxf(mrun, mx);
      float alpha = exp2fast(mrun - mnew);
      mrun = mnew;
#pragma unroll
      for (int rr = 0; rr < 4; ++rr) lrun[rr] *= alpha;
#pragma unroll
      for (int js = 0; js < 4; ++js) o[js] *= alpha;
    }
    // p = 2^(s-m); deferred per-lane l partials; P -> LDS (octet-XOR, 0-conflict)
    unsigned short* Pw = &Ps[w][0];
#pragma unroll
    for (int j = 0; j < 4; ++j) {
      int og = 2 * j + (l15 >> 3);
#pragma unroll
      for (int rr = 0; rr < 4; ++rr) {
        float p = exp2fast(sf[j][rr] - mrun);
        lrun[rr] += p;
        union { float f; unsigned int u; } cu;
        cu.f = p;
        int qr = (lg << 2) + rr;
        Pw[qr * 64 + ((og ^ (qr & 7)) * 8) + (l15 & 7)] = (unsigned short)(cu.u >> 16);
      }
    }
    // O += P V
    const unsigned short* Vc = &Vt[cur][0];
    __builtin_amdgcn_s_setprio(1);
#pragma unroll
    for (int kx = 0; kx < 2; ++kx) {
      bf16x8 ap = *(const bf16x8*)&Pw[l15 * 64 + (((kx * 4 + lg) ^ (l15 & 7)) * 8)];
#pragma unroll
      for (int js = 0; js < 4; ++js) {
        int rv = js * 16 + l15;
        bf16x8 bv = *(const bf16x8*)&Vc[rv * 64 + (((kx * 4 + lg) ^ (rv & 7)) * 8)];
        o[js] = __builtin_amdgcn_mfma_f32_16x16x32_bf16(ap, bv, o[js], 0, 0, 0);
      }
    }
    __builtin_amdgcn_s_setprio(0);
    __syncthreads();  // drains prefetch into [cur^1]; gates buffer reuse
  }

  // epilogue: reduce deferred l, normalize, store
#pragma unroll
  for (int rr = 0; rr < 4; ++rr) {
    float l = lrun[rr];
#pragma unroll
    for (int off = 1; off < 16; off <<= 1) l += __shfl_xor(l, off);
    float inv = 1.f / l;
    int tg = qseg * 64 + w * 16 + (lg << 2) + rr;
    size_t base = ((size_t)b * Tdim + tg) * Edim + h * 64;
#pragma unroll
    for (int js = 0; js < 4; ++js) Ob[base + js * 16 + l15] = f2bf(o[js][rr] * inv);
  }
}

// ---------------------------------------------------------------------------
extern "C" void kernel_launch(void* const* d_in, const int* in_sizes, int n_in,
                              void* d_out, int out_size, void* d_ws, size_t ws_size,
                              hipStream_t stream) {
  const float* queries = (const float*)d_in[0];
  const float* keys    = (const float*)d_in[1];
  const float* values  = (const float*)d_in[2];
  const float* Wq = (const float*)d_in[3];
  const float* Wk = (const float*)d_in[4];
  const float* Wv = (const float*)d_in[5];
  const float* Wo = (const float*)d_in[6];
  const float* bo = (const float*)d_in[7];
  const float* qlnw = (const float*)d_in[8];
  const float* qlnb = (const float*)d_in[9];
  const float* klnw = (const float*)d_in[10];
  const float* klnb = (const float*)d_in[11];
  float* out = (float*)d_out;

  unsigned short* Wtq = (unsigned short*)d_ws;          // 4 x 2MB
  unsigned short* Wtk = Wtq + 1024 * 1024;
  unsigned short* Wtv = Wtk + 1024 * 1024;
  unsigned short* Wto = Wtv + 1024 * 1024;
  unsigned short* Qn  = Wto + 1024 * 1024;              // [B,H,T,S]
  unsigned short* Kn  = Qn + (size_t)Mdim * Edim;       // [B,H,T,S]
  unsigned short* Vb  = Kn + (size_t)Mdim * Edim;       // [B,H,S,T] (transposed)
  unsigned short* Qa  = Vb + (size_t)Mdim * Edim;       // bf16 activations
  unsigned short* Ka  = Qa + (size_t)Mdim * Edim;
  unsigned short* Va  = Ka + (size_t)Mdim * Edim;
  unsigned short* Ob  = Qa;                             // alias: Qa dead after qkv_k

  cvt_k<<<dim3(2048, 1, 3), 256, 0, stream>>>(queries, keys, values, Qa, Ka, Va);
  wconv_k<<<dim3(32, 32, 4), dim3(32, 8), 0, stream>>>(Wq, Wk, Wv, Wo, Wtq, Wtk, Wtv, Wto);
  qkv_k<<<768, 256, 0, stream>>>(Qa, Ka, Va, Wtq, Wtk, Wtv,
                                 qlnw, qlnb, klnw, klnb, Qn, Kn, Vb);
  flash_k<<<1024, 256, 0, stream>>>(Qn, Kn, Vb, Ob);
  gemmo_k<<<512, 256, 0, stream>>>(Ob, Wto, bo, out);
}

// Round 6
// 220.718 us; speedup vs baseline: 1.2482x; 1.0353x over previous
//
#include <hip/hip_runtime.h>

#define Tdim 2048
#define Edim 1024
#define Hdim 16
#define Sdim 64
#define Mdim 4096
#define LN_EPS 1e-5f
#define QKSCALE 0.21233045007200477f  // 1024^-0.25 * sqrt(log2(e))  [log2-domain softmax]

typedef __bf16 bf16x8 __attribute__((ext_vector_type(8)));
typedef float f32x4 __attribute__((ext_vector_type(4)));

__device__ __forceinline__ unsigned short f2bf(float f) {
  union { float f; unsigned int u; } c; c.f = f;
  unsigned int u = c.u;
  return (unsigned short)((u + 0x7FFFu + ((u >> 16) & 1u)) >> 16);
}

__device__ __forceinline__ float exp2fast(float x) {
  float r;
  asm("v_exp_f32 %0, %1" : "=v"(r) : "v"(x));
  return r;
}

// async global->LDS, 16B per lane, lane-contiguous at LDS base (wave-uniform)
__device__ __forceinline__ void gl_lds16(const void* g, void* l) {
  __builtin_amdgcn_global_load_lds(
      (const __attribute__((address_space(1))) void*)g,
      (__attribute__((address_space(3))) void*)l, 16, 0, 0);
}

// pack two fp32 (as bits) -> dword of two bf16 (truncate)
__device__ __forceinline__ unsigned int pk2bf(unsigned int lo, unsigned int hi) {
  return __builtin_amdgcn_perm(hi, lo, 0x07060302u);
}

// ---------------------------------------------------------------------------
// prep: merged activation-convert + weight-transpose (one launch).
// bid < 6144  : fp32->bf16 convert of queries/keys/values (2048 blocks each)
// bid >= 6144 : transpose+convert W [K][N] fp32 -> Wt [N][K] bf16 (1024/matrix)
// ---------------------------------------------------------------------------
__global__ __launch_bounds__(256) void prep_k(
    const float* __restrict__ X0, const float* __restrict__ X1, const float* __restrict__ X2,
    unsigned short* __restrict__ Y0, unsigned short* __restrict__ Y1,
    unsigned short* __restrict__ Y2,
    const float* __restrict__ W0, const float* __restrict__ W1,
    const float* __restrict__ W2, const float* __restrict__ W3,
    unsigned short* __restrict__ O0, unsigned short* __restrict__ O1,
    unsigned short* __restrict__ O2, unsigned short* __restrict__ O3) {
  int bid = blockIdx.x, tid = threadIdx.x;
  if (bid < 6144) {
    int zi = bid >> 11, blk = bid & 2047;
    const float* X = zi == 0 ? X0 : zi == 1 ? X1 : X2;
    unsigned short* Y = zi == 0 ? Y0 : zi == 1 ? Y1 : Y2;
    size_t i = ((size_t)blk * 256 + tid) * 8;
    uint4 a = *(const uint4*)&X[i];
    uint4 b = *(const uint4*)&X[i + 4];
    uint4 o;
    o.x = pk2bf(a.x, a.y);
    o.y = pk2bf(a.z, a.w);
    o.z = pk2bf(b.x, b.y);
    o.w = pk2bf(b.z, b.w);
    *(uint4*)&Y[i] = o;
  } else {
    int wb = bid - 6144;
    int zi = wb >> 10, tile = wb & 1023;
    const float* W = zi == 0 ? W0 : zi == 1 ? W1 : zi == 2 ? W2 : W3;
    unsigned short* O = zi == 0 ? O0 : zi == 1 ? O1 : zi == 2 ? O2 : O3;
    __shared__ float t[32][33];
    int n0 = (tile & 31) * 32, k0 = (tile >> 5) * 32;
    int tx = tid & 31, ty = tid >> 5;  // 32 x 8
    for (int yy = ty; yy < 32; yy += 8)
      t[yy][tx] = W[(size_t)(k0 + yy) * Edim + n0 + tx];
    __syncthreads();
    for (int yy = ty; yy < 32; yy += 8)
      O[(size_t)(n0 + yy) * Edim + k0 + tx] = f2bf(t[tx][yy]);
  }
}

// ---------------------------------------------------------------------------
// Fused QKV GEMM (pure bf16), m97 structure: 128x128 tile, BK=32, single
// 16KB LDS buffer, 2 barriers/k-step, gl_lds both operands, 4-slot XOR
// swizzle (2-way = free). All 768 blocks co-resident (3/CU).
// z<2 : C = X*Wt^T, per-head LN * QKSCALE -> bf16 [B,H,T,S]
// z==2: operands swapped -> C = Wt*X^T = V^T -> bf16 [B,H,S,T]
// ---------------------------------------------------------------------------
__global__ __launch_bounds__(256, 4) void qkv_k(
    const unsigned short* __restrict__ Qa, const unsigned short* __restrict__ Ka,
    const unsigned short* __restrict__ Va,
    const unsigned short* __restrict__ Bq, const unsigned short* __restrict__ Bk,
    const unsigned short* __restrict__ Bv,
    const float* __restrict__ qlnw, const float* __restrict__ qlnb,
    const float* __restrict__ klnw, const float* __restrict__ klnb,
    unsigned short* __restrict__ Oq, unsigned short* __restrict__ Ok,
    unsigned short* __restrict__ Ov) {
  __shared__ unsigned short As[128 * 32];
  __shared__ unsigned short Bs[128 * 32];
  int f = blockIdx.x;
  int L = (f & 7) * 96 + (f >> 3);
  int bx = L & 7, by = (L >> 3) & 31, z = L >> 8;
  const unsigned short* A = z == 0 ? Qa : z == 1 ? Ka : Va;
  const unsigned short* Bt = z == 0 ? Bq : z == 1 ? Bk : Bv;
  const float* lnw = z == 0 ? qlnw : klnw;
  const float* lnb = z == 0 ? qlnb : klnb;
  unsigned short* obf = z == 0 ? Oq : z == 1 ? Ok : Ov;

  int tid = threadIdx.x, lane = tid & 63, w = tid >> 6;
  int wr = w >> 1, wc = w & 1;
  int lg = lane >> 4, l15 = lane & 15;
  int cr = lane >> 2, sl = lane & 3;  // staging: 16 rows x 4 slots of 16B
  int m0 = by * 128, n0 = bx * 128;

  f32x4 acc[4][4];
#pragma unroll
  for (int i = 0; i < 4; ++i)
#pragma unroll
    for (int j = 0; j < 4; ++j) acc[i][j] = f32x4{0.f, 0.f, 0.f, 0.f};

  for (int ks = 0; ks < 32; ++ks) {
    int k0 = ks * 32;
    __syncthreads();  // previous k-step's LDS reads complete
#pragma unroll
    for (int q = 0; q < 2; ++q) {
      int c = w * 2 + q, r = c * 16 + cr;
      gl_lds16(&A[(size_t)(m0 + r) * Edim + k0 + ((sl ^ (r & 3)) * 8)], &As[c * 512]);
    }
#pragma unroll
    for (int q = 0; q < 2; ++q) {
      int c = w * 2 + q, r = c * 16 + cr;
      gl_lds16(&Bt[(size_t)(n0 + r) * Edim + k0 + ((sl ^ (r & 3)) * 8)], &Bs[c * 512]);
    }
    __syncthreads();  // staged data visible (implicit vmcnt drain)
    const unsigned short* pA = (z == 2) ? &Bs[0] : &As[0];
    const unsigned short* pB = (z == 2) ? &As[0] : &Bs[0];
    bf16x8 a[4], bb[4];
#pragma unroll
    for (int i = 0; i < 4; ++i) {
      int r = wr * 64 + i * 16 + l15;
      a[i] = *(const bf16x8*)&pA[r * 32 + ((lg ^ (r & 3)) * 8)];
    }
#pragma unroll
    for (int j = 0; j < 4; ++j) {
      int r = wc * 64 + j * 16 + l15;
      bb[j] = *(const bf16x8*)&pB[r * 32 + ((lg ^ (r & 3)) * 8)];
    }
    __builtin_amdgcn_s_setprio(1);
#pragma unroll
    for (int i = 0; i < 4; ++i)
#pragma unroll
      for (int j = 0; j < 4; ++j)
        acc[i][j] = __builtin_amdgcn_mfma_f32_16x16x32_bf16(a[i], bb[j], acc[i][j], 0, 0, 0);
    __builtin_amdgcn_s_setprio(0);
  }

  if (z < 2) {
    int mb = m0 + wr * 64;
    int h = (n0 >> 6) + wc;  // wave's 64 cols == one head
#pragma unroll
    for (int i = 0; i < 4; ++i) {
#pragma unroll
      for (int r = 0; r < 4; ++r) {
        float xv[4];
#pragma unroll
        for (int j = 0; j < 4; ++j) xv[j] = acc[i][j][r];
        float sum = xv[0] + xv[1] + xv[2] + xv[3];
        float sq = xv[0] * xv[0] + xv[1] * xv[1] + xv[2] * xv[2] + xv[3] * xv[3];
#pragma unroll
        for (int off = 1; off < 16; off <<= 1) {
          sum += __shfl_xor(sum, off);
          sq += __shfl_xor(sq, off);
        }
        float mean = sum * (1.f / 64.f);
        float var = sq * (1.f / 64.f) - mean * mean;
        float rstd = rsqrtf(var + LN_EPS);
        int m = mb + i * 16 + (lg << 2) + r;
        int bb2 = m >> 11, tt = m & 2047;
        size_t base = ((size_t)(bb2 * Hdim + h) * Tdim + tt) * Sdim;
#pragma unroll
        for (int j = 0; j < 4; ++j) {
          int s = j * 16 + l15;
          float ov = ((xv[j] - mean) * rstd * lnw[s] + lnb[s]) * QKSCALE;
          obf[base + s] = f2bf(ov);
        }
      }
    }
  } else {
    // C = V^T : row = head-col (n0-block), col = token (m0-block)
#pragma unroll
    for (int i = 0; i < 4; ++i)
#pragma unroll
      for (int r = 0; r < 4; ++r) {
        int hc = n0 + wr * 64 + i * 16 + (lg << 2) + r;
        int h = hc >> 6, s = hc & 63;
#pragma unroll
        for (int j = 0; j < 4; ++j) {
          int tk = m0 + wc * 64 + j * 16 + l15;
          int bb2 = tk >> 11, tt = tk & 2047;
          obf[(((size_t)(bb2 * Hdim + h) * Sdim + s)) * Tdim + tt] = f2bf(acc[i][j][r]);
        }
      }
  }
}

// ---------------------------------------------------------------------------
// Out-projection GEMM: Y = Ob(bf16) * Wto^T + bo -> fp32.
// m97 structure: 128x64 tile, BK=32, single 12KB LDS buffer, 2 barriers/step.
// ---------------------------------------------------------------------------
__global__ __launch_bounds__(256, 4) void gemmo_k(
    const unsigned short* __restrict__ A, const unsigned short* __restrict__ Bt,
    const float* __restrict__ bias, float* __restrict__ ofp) {
  __shared__ unsigned short As[128 * 32];
  __shared__ unsigned short Bs[64 * 32];
  int f = blockIdx.x;
  int L = (f & 7) * 64 + (f >> 3);
  int bx = L & 15, by = L >> 4;
  int tid = threadIdx.x, lane = tid & 63, w = tid >> 6;
  int wr = w >> 1, wc = w & 1;
  int lg = lane >> 4, l15 = lane & 15;
  int cr = lane >> 2, sl = lane & 3;
  int m0 = by * 128, n0 = bx * 64;

  f32x4 acc[4][2];
#pragma unroll
  for (int i = 0; i < 4; ++i)
#pragma unroll
    for (int j = 0; j < 2; ++j) acc[i][j] = f32x4{0.f, 0.f, 0.f, 0.f};

  for (int ks = 0; ks < 32; ++ks) {
    int k0 = ks * 32;
    __syncthreads();
#pragma unroll
    for (int q = 0; q < 2; ++q) {
      int c = w * 2 + q, r = c * 16 + cr;
      gl_lds16(&A[(size_t)(m0 + r) * Edim + k0 + ((sl ^ (r & 3)) * 8)], &As[c * 512]);
    }
    {
      int c = w, r = c * 16 + cr;
      gl_lds16(&Bt[(size_t)(n0 + r) * Edim + k0 + ((sl ^ (r & 3)) * 8)], &Bs[c * 512]);
    }
    __syncthreads();
    bf16x8 a[4], bb[2];
#pragma unroll
    for (int i = 0; i < 4; ++i) {
      int r = wr * 64 + i * 16 + l15;
      a[i] = *(const bf16x8*)&As[r * 32 + ((lg ^ (r & 3)) * 8)];
    }
#pragma unroll
    for (int j = 0; j < 2; ++j) {
      int r = wc * 32 + j * 16 + l15;
      bb[j] = *(const bf16x8*)&Bs[r * 32 + ((lg ^ (r & 3)) * 8)];
    }
    __builtin_amdgcn_s_setprio(1);
#pragma unroll
    for (int i = 0; i < 4; ++i)
#pragma unroll
      for (int j = 0; j < 2; ++j)
        acc[i][j] = __builtin_amdgcn_mfma_f32_16x16x32_bf16(a[i], bb[j], acc[i][j], 0, 0, 0);
    __builtin_amdgcn_s_setprio(0);
  }

  int mb = m0 + wr * 64, nb = n0 + wc * 32;
#pragma unroll
  for (int i = 0; i < 4; ++i)
#pragma unroll
    for (int r = 0; r < 4; ++r) {
      int m = mb + i * 16 + (lg << 2) + r;
#pragma unroll
      for (int j = 0; j < 2; ++j) {
        int n = nb + j * 16 + l15;
        ofp[(size_t)m * Edim + n] = acc[i][j][r] + bias[n];
      }
    }
}

// ---------------------------------------------------------------------------
// Flash attention, log2-domain. 4 waves x 16 q-rows (QBLK=64), KVBLK=64.
// Grid: 1024 blocks, one q-segment each, dispatched longest-first for greedy
// balance; bh = 4*(wid&7) + (idx&3) keeps each XCD's K/V set at 2MB (L2-fit).
// K,V double-buffered via gl_lds (V pre-transposed to [B,H,S,T] by qkv_k).
// Joint running-max per lane-group; deferred l-sum; one barrier per tile.
// ---------------------------------------------------------------------------
__global__ __launch_bounds__(256) void flash_k(
    const unsigned short* __restrict__ Qn, const unsigned short* __restrict__ Kn,
    const unsigned short* __restrict__ Vb, unsigned short* __restrict__ Ob) {
  __shared__ unsigned short Qs[4096];
  __shared__ unsigned short Ks[2][4096];
  __shared__ unsigned short Vt[2][4096];
  __shared__ unsigned short Ps[4][1024];

  int wid0 = blockIdx.x;
  int idx = wid0 >> 3;
  int bh = (wid0 & 7) * 4 + (idx & 3);   // 4 heads per XCD -> K/V 2MB in L2
  int qseg = 31 - (idx >> 2);            // longest blocks dispatch first
  int nt = qseg + 1;

  int tid = threadIdx.x, lane = tid & 63, w = tid >> 6;
  int lg = lane >> 4, l15 = lane & 15;
  int lr = lane >> 3, ls = lane & 7;
  const unsigned short* Qg = Qn + ((size_t)bh * Tdim + (size_t)qseg * 64) * Sdim;
  const unsigned short* Kg = Kn + (size_t)bh * Tdim * Sdim;  // [t][s]
  const unsigned short* Vg = Vb + (size_t)bh * Sdim * Tdim;  // [s][t]
  int b = bh >> 4, h = bh & 15;

  auto stageK = [&](int tt, int kb) {
    const unsigned short* src = Kg + (size_t)tt * 64 * 64;
#pragma unroll
    for (int q = 0; q < 2; ++q) {
      int c = w * 2 + q, r = c * 8 + lr;
      gl_lds16(&src[r * 64 + ((ls ^ (r & 7)) * 8)], &Ks[kb][c * 512]);
    }
  };
  auto stageV = [&](int tt, int vb) {
    const unsigned short* src = Vg + tt * 64;  // rows = s (stride Tdim), cols = kv
#pragma unroll
    for (int q = 0; q < 2; ++q) {
      int c = w * 2 + q, r = c * 8 + lr;
      gl_lds16(&src[(size_t)r * Tdim + ((ls ^ (r & 7)) * 8)], &Vt[vb][c * 512]);
    }
  };

  // prologue staging (async)
#pragma unroll
  for (int q = 0; q < 2; ++q) {
    int c = w * 2 + q, r = c * 8 + lr;
    gl_lds16(&Qg[r * 64 + ((ls ^ (r & 7)) * 8)], &Qs[c * 512]);
  }
  stageK(0, 0);
  stageV(0, 0);

  float mrun = -1e30f;
  float lrun[4] = {0.f, 0.f, 0.f, 0.f};
  f32x4 o[4];
#pragma unroll
  for (int js = 0; js < 4; ++js) o[js] = f32x4{0.f, 0.f, 0.f, 0.f};

  __syncthreads();

  bf16x8 aq[2];
  {
    int rq = w * 16 + l15;
    aq[0] = *(const bf16x8*)&Qs[rq * 64 + ((lg ^ (rq & 7)) * 8)];
    aq[1] = *(const bf16x8*)&Qs[rq * 64 + (((4 + lg) ^ (rq & 7)) * 8)];
  }

  for (int t = 0; t < nt; ++t) {
    int cur = t & 1;
    if (t + 1 < nt) {  // async prefetch; drained by end-of-iter barrier
      stageK(t + 1, cur ^ 1);
      stageV(t + 1, cur ^ 1);
    }
    // S = Q K^T (log2-domain scores; scale folded into Q,K)
    f32x4 sf[4];
#pragma unroll
    for (int j = 0; j < 4; ++j) sf[j] = f32x4{0.f, 0.f, 0.f, 0.f};
    const unsigned short* Kc = &Ks[cur][0];
    __builtin_amdgcn_s_setprio(1);
#pragma unroll
    for (int kx = 0; kx < 2; ++kx) {
#pragma unroll
      for (int j = 0; j < 4; ++j) {
        int rk = j * 16 + l15;
        bf16x8 bk = *(const bf16x8*)&Kc[rk * 64 + (((kx * 4 + lg) ^ (rk & 7)) * 8)];
        sf[j] = __builtin_amdgcn_mfma_f32_16x16x32_bf16(aq[kx], bk, sf[j], 0, 0, 0);
      }
    }
    __builtin_amdgcn_s_setprio(0);
    if (t == qseg) {  // causal diagonal tile
#pragma unroll
      for (int j = 0; j < 4; ++j)
#pragma unroll
        for (int rr = 0; rr < 4; ++rr)
          if (j * 16 + l15 > w * 16 + (lg << 2) + rr) sf[j][rr] = -1e30f;
    }
    // joint max over lane-group's 4 rows (any shared reference max is valid)
    float mx = -3e38f;
#pragma unroll
    for (int j = 0; j < 4; ++j)
#pragma unroll
      for (int rr = 0; rr < 4; ++rr) mx = fmaxf(mx, sf[j][rr]);
#pragma unroll
    for (int off = 1; off < 16; off <<= 1) mx = fmaxf(mx, __shfl_xor(mx, off));
    if (__any(mx > mrun + 8.f)) {  // defer-max: rescale only on real growth
      float mnew = fmaxf(mrun, mx);
      float alpha = exp2fast(mrun - mnew);
      mrun = mnew;
#pragma unroll
      for (int rr = 0; rr < 4; ++rr) lrun[rr] *= alpha;
#pragma unroll
      for (int js = 0; js < 4; ++js) o[js] *= alpha;
    }
    // p = 2^(s-m); deferred per-lane l partials; P -> LDS (octet-XOR, 0-conflict)
    unsigned short* Pw = &Ps[w][0];
#pragma unroll
    for (int j = 0; j < 4; ++j) {
      int og = 2 * j + (l15 >> 3);
#pragma unroll
      for (int rr = 0; rr < 4; ++rr) {
        float p = exp2fast(sf[j][rr] - mrun);
        lrun[rr] += p;
        union { float f; unsigned int u; } cu;
        cu.f = p;
        int qr = (lg << 2) + rr;
        Pw[qr * 64 + ((og ^ (qr & 7)) * 8) + (l15 & 7)] = (unsigned short)(cu.u >> 16);
      }
    }
    // O += P V
    const unsigned short* Vc = &Vt[cur][0];
    __builtin_amdgcn_s_setprio(1);
#pragma unroll
    for (int kx = 0; kx < 2; ++kx) {
      bf16x8 ap = *(const bf16x8*)&Pw[l15 * 64 + (((kx * 4 + lg) ^ (l15 & 7)) * 8)];
#pragma unroll
      for (int js = 0; js < 4; ++js) {
        int rv = js * 16 + l15;
        bf16x8 bv = *(const bf16x8*)&Vc[rv * 64 + (((kx * 4 + lg) ^ (rv & 7)) * 8)];
        o[js] = __builtin_amdgcn_mfma_f32_16x16x32_bf16(ap, bv, o[js], 0, 0, 0);
      }
    }
    __builtin_amdgcn_s_setprio(0);
    __syncthreads();  // drains prefetch into [cur^1]; gates buffer reuse
  }

  // epilogue: reduce deferred l, normalize, store
#pragma unroll
  for (int rr = 0; rr < 4; ++rr) {
    float l = lrun[rr];
#pragma unroll
    for (int off = 1; off < 16; off <<= 1) l += __shfl_xor(l, off);
    float inv = 1.f / l;
    int tg = qseg * 64 + w * 16 + (lg << 2) + rr;
    size_t base = ((size_t)b * Tdim + tg) * Edim + h * 64;
#pragma unroll
    for (int js = 0; js < 4; ++js) Ob[base + js * 16 + l15] = f2bf(o[js][rr] * inv);
  }
}

// ---------------------------------------------------------------------------
extern "C" void kernel_launch(void* const* d_in, const int* in_sizes, int n_in,
                              void* d_out, int out_size, void* d_ws, size_t ws_size,
                              hipStream_t stream) {
  const float* queries = (const float*)d_in[0];
  const float* keys    = (const float*)d_in[1];
  const float* values  = (const float*)d_in[2];
  const float* Wq = (const float*)d_in[3];
  const float* Wk = (const float*)d_in[4];
  const float* Wv = (const float*)d_in[5];
  const float* Wo = (const float*)d_in[6];
  const float* bo = (const float*)d_in[7];
  const float* qlnw = (const float*)d_in[8];
  const float* qlnb = (const float*)d_in[9];
  const float* klnw = (const float*)d_in[10];
  const float* klnb = (const float*)d_in[11];
  float* out = (float*)d_out;

  unsigned short* Wtq = (unsigned short*)d_ws;          // 4 x 2MB
  unsigned short* Wtk = Wtq + 1024 * 1024;
  unsigned short* Wtv = Wtk + 1024 * 1024;
  unsigned short* Wto = Wtv + 1024 * 1024;
  unsigned short* Qn  = Wto + 1024 * 1024;              // [B,H,T,S]
  unsigned short* Kn  = Qn + (size_t)Mdim * Edim;       // [B,H,T,S]
  unsigned short* Vb  = Kn + (size_t)Mdim * Edim;       // [B,H,S,T] (transposed)
  unsigned short* Qa  = Vb + (size_t)Mdim * Edim;       // bf16 activations
  unsigned short* Ka  = Qa + (size_t)Mdim * Edim;
  unsigned short* Va  = Ka + (size_t)Mdim * Edim;
  unsigned short* Ob  = Qa;                             // alias: Qa dead after qkv_k

  prep_k<<<10240, 256, 0, stream>>>(queries, keys, values, Qa, Ka, Va,
                                    Wq, Wk, Wv, Wo, Wtq, Wtk, Wtv, Wto);
  qkv_k<<<768, 256, 0, stream>>>(Qa, Ka, Va, Wtq, Wtk, Wtv,
                                 qlnw, qlnb, klnw, klnb, Qn, Kn, Vb);
  flash_k<<<1024, 256, 0, stream>>>(Qn, Kn, Vb, Ob);
  gemmo_k<<<512, 256, 0, stream>>>(Ob, Wto, bo, out);
}

// Round 7
// 213.315 us; speedup vs baseline: 1.2915x; 1.0347x over previous
//
#include <hip/hip_runtime.h>

#define Tdim 2048
#define Edim 1024
#define Hdim 16
#define Sdim 64
#define Mdim 4096
#define LN_EPS 1e-5f
#define QKSCALE 0.21233045007200477f  // 1024^-0.25 * sqrt(log2(e))  [log2-domain softmax]

typedef __bf16 bf16x8 __attribute__((ext_vector_type(8)));
typedef float f32x4 __attribute__((ext_vector_type(4)));

__device__ __forceinline__ unsigned short f2bf(float f) {
  union { float f; unsigned int u; } c; c.f = f;
  unsigned int u = c.u;
  return (unsigned short)((u + 0x7FFFu + ((u >> 16) & 1u)) >> 16);
}

__device__ __forceinline__ float exp2fast(float x) {
  float r;
  asm("v_exp_f32 %0, %1" : "=v"(r) : "v"(x));
  return r;
}

// async global->LDS, 16B per lane, lane-contiguous at LDS base (wave-uniform)
__device__ __forceinline__ void gl_lds16(const void* g, void* l) {
  __builtin_amdgcn_global_load_lds(
      (const __attribute__((address_space(1))) void*)g,
      (__attribute__((address_space(3))) void*)l, 16, 0, 0);
}

// pack two fp32 (as bits) -> dword of two bf16 (truncate)
__device__ __forceinline__ unsigned int pk2bf(unsigned int lo, unsigned int hi) {
  return __builtin_amdgcn_perm(hi, lo, 0x07060302u);
}

// ---------------------------------------------------------------------------
// prep: merged activation-convert + weight-transpose (one launch).
// ---------------------------------------------------------------------------
__global__ __launch_bounds__(256) void prep_k(
    const float* __restrict__ X0, const float* __restrict__ X1, const float* __restrict__ X2,
    unsigned short* __restrict__ Y0, unsigned short* __restrict__ Y1,
    unsigned short* __restrict__ Y2,
    const float* __restrict__ W0, const float* __restrict__ W1,
    const float* __restrict__ W2, const float* __restrict__ W3,
    unsigned short* __restrict__ O0, unsigned short* __restrict__ O1,
    unsigned short* __restrict__ O2, unsigned short* __restrict__ O3) {
  int bid = blockIdx.x, tid = threadIdx.x;
  if (bid < 6144) {
    int zi = bid >> 11, blk = bid & 2047;
    const float* X = zi == 0 ? X0 : zi == 1 ? X1 : X2;
    unsigned short* Y = zi == 0 ? Y0 : zi == 1 ? Y1 : Y2;
    size_t i = ((size_t)blk * 256 + tid) * 8;
    uint4 a = *(const uint4*)&X[i];
    uint4 b = *(const uint4*)&X[i + 4];
    uint4 o;
    o.x = pk2bf(a.x, a.y);
    o.y = pk2bf(a.z, a.w);
    o.z = pk2bf(b.x, b.y);
    o.w = pk2bf(b.z, b.w);
    *(uint4*)&Y[i] = o;
  } else {
    int wb = bid - 6144;
    int zi = wb >> 10, tile = wb & 1023;
    const float* W = zi == 0 ? W0 : zi == 1 ? W1 : zi == 2 ? W2 : W3;
    unsigned short* O = zi == 0 ? O0 : zi == 1 ? O1 : zi == 2 ? O2 : O3;
    __shared__ float t[32][33];
    int n0 = (tile & 31) * 32, k0 = (tile >> 5) * 32;
    int tx = tid & 31, ty = tid >> 5;  // 32 x 8
    for (int yy = ty; yy < 32; yy += 8)
      t[yy][tx] = W[(size_t)(k0 + yy) * Edim + n0 + tx];
    __syncthreads();
    for (int yy = ty; yy < 32; yy += 8)
      O[(size_t)(n0 + yy) * Edim + k0 + tx] = f2bf(t[tx][yy]);
  }
}

// ---------------------------------------------------------------------------
// Fused QKV GEMM (pure bf16), m97 structure: 128x128 tile, BK=32, single
// 16KB LDS buffer, 2 barriers/k-step, gl_lds both operands.
// z<2 : C = X*Wt^T, per-head LN * QKSCALE -> bf16 [B,H,T,S]
// z==2: operands swapped -> C = Wt*X^T = V^T -> bf16 [B,H,S,T]
// ---------------------------------------------------------------------------
__global__ __launch_bounds__(256, 4) void qkv_k(
    const unsigned short* __restrict__ Qa, const unsigned short* __restrict__ Ka,
    const unsigned short* __restrict__ Va,
    const unsigned short* __restrict__ Bq, const unsigned short* __restrict__ Bk,
    const unsigned short* __restrict__ Bv,
    const float* __restrict__ qlnw, const float* __restrict__ qlnb,
    const float* __restrict__ klnw, const float* __restrict__ klnb,
    unsigned short* __restrict__ Oq, unsigned short* __restrict__ Ok,
    unsigned short* __restrict__ Ov) {
  __shared__ unsigned short As[128 * 32];
  __shared__ unsigned short Bs[128 * 32];
  int f = blockIdx.x;
  int L = (f & 7) * 96 + (f >> 3);
  int bx = L & 7, by = (L >> 3) & 31, z = L >> 8;
  const unsigned short* A = z == 0 ? Qa : z == 1 ? Ka : Va;
  const unsigned short* Bt = z == 0 ? Bq : z == 1 ? Bk : Bv;
  const float* lnw = z == 0 ? qlnw : klnw;
  const float* lnb = z == 0 ? qlnb : klnb;
  unsigned short* obf = z == 0 ? Oq : z == 1 ? Ok : Ov;

  int tid = threadIdx.x, lane = tid & 63, w = tid >> 6;
  int wr = w >> 1, wc = w & 1;
  int lg = lane >> 4, l15 = lane & 15;
  int cr = lane >> 2, sl = lane & 3;  // staging: 16 rows x 4 slots of 16B
  int m0 = by * 128, n0 = bx * 128;

  f32x4 acc[4][4];
#pragma unroll
  for (int i = 0; i < 4; ++i)
#pragma unroll
    for (int j = 0; j < 4; ++j) acc[i][j] = f32x4{0.f, 0.f, 0.f, 0.f};

  for (int ks = 0; ks < 32; ++ks) {
    int k0 = ks * 32;
    __syncthreads();  // previous k-step's LDS reads complete
#pragma unroll
    for (int q = 0; q < 2; ++q) {
      int c = w * 2 + q, r = c * 16 + cr;
      gl_lds16(&A[(size_t)(m0 + r) * Edim + k0 + ((sl ^ (r & 3)) * 8)], &As[c * 512]);
    }
#pragma unroll
    for (int q = 0; q < 2; ++q) {
      int c = w * 2 + q, r = c * 16 + cr;
      gl_lds16(&Bt[(size_t)(n0 + r) * Edim + k0 + ((sl ^ (r & 3)) * 8)], &Bs[c * 512]);
    }
    __syncthreads();  // staged data visible (implicit vmcnt drain)
    const unsigned short* pA = (z == 2) ? &Bs[0] : &As[0];
    const unsigned short* pB = (z == 2) ? &As[0] : &Bs[0];
    bf16x8 a[4], bb[4];
#pragma unroll
    for (int i = 0; i < 4; ++i) {
      int r = wr * 64 + i * 16 + l15;
      a[i] = *(const bf16x8*)&pA[r * 32 + ((lg ^ (r & 3)) * 8)];
    }
#pragma unroll
    for (int j = 0; j < 4; ++j) {
      int r = wc * 64 + j * 16 + l15;
      bb[j] = *(const bf16x8*)&pB[r * 32 + ((lg ^ (r & 3)) * 8)];
    }
    __builtin_amdgcn_s_setprio(1);
#pragma unroll
    for (int i = 0; i < 4; ++i)
#pragma unroll
      for (int j = 0; j < 4; ++j)
        acc[i][j] = __builtin_amdgcn_mfma_f32_16x16x32_bf16(a[i], bb[j], acc[i][j], 0, 0, 0);
    __builtin_amdgcn_s_setprio(0);
  }

  if (z < 2) {
    int mb = m0 + wr * 64;
    int h = (n0 >> 6) + wc;  // wave's 64 cols == one head
#pragma unroll
    for (int i = 0; i < 4; ++i) {
#pragma unroll
      for (int r = 0; r < 4; ++r) {
        float xv[4];
#pragma unroll
        for (int j = 0; j < 4; ++j) xv[j] = acc[i][j][r];
        float sum = xv[0] + xv[1] + xv[2] + xv[3];
        float sq = xv[0] * xv[0] + xv[1] * xv[1] + xv[2] * xv[2] + xv[3] * xv[3];
#pragma unroll
        for (int off = 1; off < 16; off <<= 1) {
          sum += __shfl_xor(sum, off);
          sq += __shfl_xor(sq, off);
        }
        float mean = sum * (1.f / 64.f);
        float var = sq * (1.f / 64.f) - mean * mean;
        float rstd = rsqrtf(var + LN_EPS);
        int m = mb + i * 16 + (lg << 2) + r;
        int bb2 = m >> 11, tt = m & 2047;
        size_t base = ((size_t)(bb2 * Hdim + h) * Tdim + tt) * Sdim;
#pragma unroll
        for (int j = 0; j < 4; ++j) {
          int s = j * 16 + l15;
          float ov = ((xv[j] - mean) * rstd * lnw[s] + lnb[s]) * QKSCALE;
          obf[base + s] = f2bf(ov);
        }
      }
    }
  } else {
    // C = V^T : row = head-col (n0-block), col = token (m0-block)
#pragma unroll
    for (int i = 0; i < 4; ++i)
#pragma unroll
      for (int r = 0; r < 4; ++r) {
        int hc = n0 + wr * 64 + i * 16 + (lg << 2) + r;
        int h = hc >> 6, s = hc & 63;
#pragma unroll
        for (int j = 0; j < 4; ++j) {
          int tk = m0 + wc * 64 + j * 16 + l15;
          int bb2 = tk >> 11, tt = tk & 2047;
          obf[(((size_t)(bb2 * Hdim + h) * Sdim + s)) * Tdim + tt] = f2bf(acc[i][j][r]);
        }
      }
  }
}

// ---------------------------------------------------------------------------
// Out-projection GEMM: Y = Ob(bf16) * Wto^T + bo -> fp32.
// m97 structure: 128x64 tile, BK=32, single 12KB LDS buffer, 2 barriers/step.
// ---------------------------------------------------------------------------
__global__ __launch_bounds__(256, 4) void gemmo_k(
    const unsigned short* __restrict__ A, const unsigned short* __restrict__ Bt,
    const float* __restrict__ bias, float* __restrict__ ofp) {
  __shared__ unsigned short As[128 * 32];
  __shared__ unsigned short Bs[64 * 32];
  int f = blockIdx.x;
  int L = (f & 7) * 64 + (f >> 3);
  int bx = L & 15, by = L >> 4;
  int tid = threadIdx.x, lane = tid & 63, w = tid >> 6;
  int wr = w >> 1, wc = w & 1;
  int lg = lane >> 4, l15 = lane & 15;
  int cr = lane >> 2, sl = lane & 3;
  int m0 = by * 128, n0 = bx * 64;

  f32x4 acc[4][2];
#pragma unroll
  for (int i = 0; i < 4; ++i)
#pragma unroll
    for (int j = 0; j < 2; ++j) acc[i][j] = f32x4{0.f, 0.f, 0.f, 0.f};

  for (int ks = 0; ks < 32; ++ks) {
    int k0 = ks * 32;
    __syncthreads();
#pragma unroll
    for (int q = 0; q < 2; ++q) {
      int c = w * 2 + q, r = c * 16 + cr;
      gl_lds16(&A[(size_t)(m0 + r) * Edim + k0 + ((sl ^ (r & 3)) * 8)], &As[c * 512]);
    }
    {
      int c = w, r = c * 16 + cr;
      gl_lds16(&Bt[(size_t)(n0 + r) * Edim + k0 + ((sl ^ (r & 3)) * 8)], &Bs[c * 512]);
    }
    __syncthreads();
    bf16x8 a[4], bb[2];
#pragma unroll
    for (int i = 0; i < 4; ++i) {
      int r = wr * 64 + i * 16 + l15;
      a[i] = *(const bf16x8*)&As[r * 32 + ((lg ^ (r & 3)) * 8)];
    }
#pragma unroll
    for (int j = 0; j < 2; ++j) {
      int r = wc * 32 + j * 16 + l15;
      bb[j] = *(const bf16x8*)&Bs[r * 32 + ((lg ^ (r & 3)) * 8)];
    }
    __builtin_amdgcn_s_setprio(1);
#pragma unroll
    for (int i = 0; i < 4; ++i)
#pragma unroll
      for (int j = 0; j < 2; ++j)
        acc[i][j] = __builtin_amdgcn_mfma_f32_16x16x32_bf16(a[i], bb[j], acc[i][j], 0, 0, 0);
    __builtin_amdgcn_s_setprio(0);
  }

  int mb = m0 + wr * 64, nb = n0 + wc * 32;
#pragma unroll
  for (int i = 0; i < 4; ++i)
#pragma unroll
    for (int r = 0; r < 4; ++r) {
      int m = mb + i * 16 + (lg << 2) + r;
#pragma unroll
      for (int j = 0; j < 2; ++j) {
        int n = nb + j * 16 + l15;
        ofp[(size_t)m * Edim + n] = acc[i][j][r] + bias[n];
      }
    }
}

// ---------------------------------------------------------------------------
// Flash attention, log2-domain, SWAPPED QK^T (S^T = mfma(K, Q)):
// each lane's 16 scores belong to ONE q-row (q = l15) -> scalar m/l stats,
// 2-shfl max reduce, P written as 4x ds_write_b64 (bank-uniform XOR swizzle).
// 4 waves x 16 q-rows (QBLK=64), KVBLK=64; K,V dbuf via gl_lds; 1 barrier/tile.
// ---------------------------------------------------------------------------
__global__ __launch_bounds__(256) void flash_k(
    const unsigned short* __restrict__ Qn, const unsigned short* __restrict__ Kn,
    const unsigned short* __restrict__ Vb, unsigned short* __restrict__ Ob) {
  __shared__ unsigned short Qs[4096];
  __shared__ unsigned short Ks[2][4096];
  __shared__ unsigned short Vt[2][4096];
  __shared__ unsigned short Ps[4][1024];  // per-wave P: 16 rows(q) x 128B(kv)

  int wid0 = blockIdx.x;
  int idx = wid0 >> 3;
  int bh = (wid0 & 7) * 4 + (idx & 3);   // 4 heads per XCD -> K/V 2MB in L2
  int qseg = 31 - (idx >> 2);            // longest blocks dispatch first
  int nt = qseg + 1;

  int tid = threadIdx.x, lane = tid & 63, w = tid >> 6;
  int lg = lane >> 4, l15 = lane & 15;
  int lr = lane >> 3, ls = lane & 7;
  const unsigned short* Qg = Qn + ((size_t)bh * Tdim + (size_t)qseg * 64) * Sdim;
  const unsigned short* Kg = Kn + (size_t)bh * Tdim * Sdim;  // [t][s]
  const unsigned short* Vg = Vb + (size_t)bh * Sdim * Tdim;  // [s][t]
  int b = bh >> 4, h = bh & 15;

  auto stageK = [&](int tt, int kb) {
    const unsigned short* src = Kg + (size_t)tt * 64 * 64;
#pragma unroll
    for (int q = 0; q < 2; ++q) {
      int c = w * 2 + q, r = c * 8 + lr;
      gl_lds16(&src[r * 64 + ((ls ^ (r & 7)) * 8)], &Ks[kb][c * 512]);
    }
  };
  auto stageV = [&](int tt, int vb) {
    const unsigned short* src = Vg + tt * 64;  // rows = s (stride Tdim), cols = kv
#pragma unroll
    for (int q = 0; q < 2; ++q) {
      int c = w * 2 + q, r = c * 8 + lr;
      gl_lds16(&src[(size_t)r * Tdim + ((ls ^ (r & 7)) * 8)], &Vt[vb][c * 512]);
    }
  };

  // prologue staging (async)
#pragma unroll
  for (int q = 0; q < 2; ++q) {
    int c = w * 2 + q, r = c * 8 + lr;
    gl_lds16(&Qg[r * 64 + ((ls ^ (r & 7)) * 8)], &Qs[c * 512]);
  }
  stageK(0, 0);
  stageV(0, 0);

  float mrun = -1e30f;  // running max for q = l15 (log2 domain)
  float lrun = 0.f;     // per-lane partial denominator for q = l15
  f32x4 o[4];
#pragma unroll
  for (int js = 0; js < 4; ++js) o[js] = f32x4{0.f, 0.f, 0.f, 0.f};

  __syncthreads();

  bf16x8 aq[2];  // Q fragment (B-operand): rows q = w*16 + l15
  {
    int rq = w * 16 + l15;
    aq[0] = *(const bf16x8*)&Qs[rq * 64 + ((lg ^ (rq & 7)) * 8)];
    aq[1] = *(const bf16x8*)&Qs[rq * 64 + (((4 + lg) ^ (rq & 7)) * 8)];
  }
  unsigned int swz = (unsigned)(l15 & 7) << 4;  // P-row XOR key

  for (int t = 0; t < nt; ++t) {
    int cur = t & 1;
    if (t + 1 < nt) {  // async prefetch; drained by end-of-iter barrier
      stageK(t + 1, cur ^ 1);
      stageV(t + 1, cur ^ 1);
    }
    // S^T = K Q^T : sf[j][rr] = S[kv = t*64 + j*16 + lg*4 + rr][q = w*16 + l15]
    f32x4 sf[4];
#pragma unroll
    for (int j = 0; j < 4; ++j) sf[j] = f32x4{0.f, 0.f, 0.f, 0.f};
    const unsigned short* Kc = &Ks[cur][0];
    __builtin_amdgcn_s_setprio(1);
#pragma unroll
    for (int kx = 0; kx < 2; ++kx) {
#pragma unroll
      for (int j = 0; j < 4; ++j) {
        int rk = j * 16 + l15;
        bf16x8 ak = *(const bf16x8*)&Kc[rk * 64 + (((kx * 4 + lg) ^ (rk & 7)) * 8)];
        sf[j] = __builtin_amdgcn_mfma_f32_16x16x32_bf16(ak, aq[kx], sf[j], 0, 0, 0);
      }
    }
    __builtin_amdgcn_s_setprio(0);
    if (t == qseg) {  // causal diagonal tile: mask kv > q
#pragma unroll
      for (int j = 0; j < 4; ++j)
#pragma unroll
        for (int rr = 0; rr < 4; ++rr)
          if (j * 16 + (lg << 2) + rr > w * 16 + l15) sf[j][rr] = -1e30f;
    }
    // per-q max: 15 fmax in-lane + 2 shfl across the 4 lg-lanes of this q
    float mx = fmaxf(fmaxf(fmaxf(sf[0][0], sf[0][1]), fmaxf(sf[0][2], sf[0][3])),
                     fmaxf(fmaxf(sf[1][0], sf[1][1]), fmaxf(sf[1][2], sf[1][3])));
    mx = fmaxf(mx, fmaxf(fmaxf(fmaxf(sf[2][0], sf[2][1]), fmaxf(sf[2][2], sf[2][3])),
                         fmaxf(fmaxf(sf[3][0], sf[3][1]), fmaxf(sf[3][2], sf[3][3]))));
    mx = fmaxf(mx, __shfl_xor(mx, 16));
    mx = fmaxf(mx, __shfl_xor(mx, 32));
    if (__any(mx > mrun + 8.f)) {  // defer-max: rescale only on real growth
      float mnew = fmaxf(mrun, mx);
      float alpha = exp2fast(mrun - mnew);
      mrun = mnew;
      lrun *= alpha;
      float ar[4];
#pragma unroll
      for (int rr = 0; rr < 4; ++rr)
        ar[rr] = __shfl(alpha, (lg << 4) | ((lg << 2) + rr));
#pragma unroll
      for (int js = 0; js < 4; ++js)
#pragma unroll
        for (int rr = 0; rr < 4; ++rr) o[js][rr] *= ar[rr];
    }
    // p = 2^(s-m): 4 consecutive kv per j -> packed ds_write_b64
    unsigned short* Pw = &Ps[w][0];
#pragma unroll
    for (int j = 0; j < 4; ++j) {
      float p0 = exp2fast(sf[j][0] - mrun);
      float p1 = exp2fast(sf[j][1] - mrun);
      float p2 = exp2fast(sf[j][2] - mrun);
      float p3 = exp2fast(sf[j][3] - mrun);
      lrun += (p0 + p1) + (p2 + p3);
      union { float f; unsigned int u; } c0{p0}, c1{p1}, c2{p2}, c3{p3};
      uint2 wv;
      wv.x = pk2bf(c0.u, c1.u);
      wv.y = pk2bf(c2.u, c3.u);
      *(uint2*)((char*)Pw + l15 * 128 + ((j * 32 + lg * 8) ^ swz)) = wv;
    }
    // O += P V  (A = P rows q, B = V^T rows s)
    const unsigned short* Vc = &Vt[cur][0];
    __builtin_amdgcn_s_setprio(1);
#pragma unroll
    for (int kx = 0; kx < 2; ++kx) {
      bf16x8 ap = *(const bf16x8*)((char*)Pw + l15 * 128 + ((kx * 64 + lg * 16) ^ swz));
#pragma unroll
      for (int js = 0; js < 4; ++js) {
        int rv = js * 16 + l15;
        bf16x8 bv = *(const bf16x8*)&Vc[rv * 64 + (((kx * 4 + lg) ^ (rv & 7)) * 8)];
        o[js] = __builtin_amdgcn_mfma_f32_16x16x32_bf16(ap, bv, o[js], 0, 0, 0);
      }
    }
    __builtin_amdgcn_s_setprio(0);
    __syncthreads();  // drains prefetch into [cur^1]; gates buffer reuse
  }

  // epilogue: reduce l across lg-lanes, fetch per-o-row inverse, store
  float l = lrun;
  l += __shfl_xor(l, 16);
  l += __shfl_xor(l, 32);
  float inv = 1.f / l;  // valid for q = l15
#pragma unroll
  for (int rr = 0; rr < 4; ++rr) {
    float invr = __shfl(inv, (lg << 4) | ((lg << 2) + rr));
    int tg = qseg * 64 + w * 16 + (lg << 2) + rr;
    size_t base = ((size_t)b * Tdim + tg) * Edim + h * 64;
#pragma unroll
    for (int js = 0; js < 4; ++js) Ob[base + js * 16 + l15] = f2bf(o[js][rr] * invr);
  }
}

// ---------------------------------------------------------------------------
extern "C" void kernel_launch(void* const* d_in, const int* in_sizes, int n_in,
                              void* d_out, int out_size, void* d_ws, size_t ws_size,
                              hipStream_t stream) {
  const float* queries = (const float*)d_in[0];
  const float* keys    = (const float*)d_in[1];
  const float* values  = (const float*)d_in[2];
  const float* Wq = (const float*)d_in[3];
  const float* Wk = (const float*)d_in[4];
  const float* Wv = (const float*)d_in[5];
  const float* Wo = (const float*)d_in[6];
  const float* bo = (const float*)d_in[7];
  const float* qlnw = (const float*)d_in[8];
  const float* qlnb = (const float*)d_in[9];
  const float* klnw = (const float*)d_in[10];
  const float* klnb = (const float*)d_in[11];
  float* out = (float*)d_out;

  unsigned short* Wtq = (unsigned short*)d_ws;          // 4 x 2MB
  unsigned short* Wtk = Wtq + 1024 * 1024;
  unsigned short* Wtv = Wtk + 1024 * 1024;
  unsigned short* Wto = Wtv + 1024 * 1024;
  unsigned short* Qn  = Wto + 1024 * 1024;              // [B,H,T,S]
  unsigned short* Kn  = Qn + (size_t)Mdim * Edim;       // [B,H,T,S]
  unsigned short* Vb  = Kn + (size_t)Mdim * Edim;       // [B,H,S,T] (transposed)
  unsigned short* Qa  = Vb + (size_t)Mdim * Edim;       // bf16 activations
  unsigned short* Ka  = Qa + (size_t)Mdim * Edim;
  unsigned short* Va  = Ka + (size_t)Mdim * Edim;
  unsigned short* Ob  = Qa;                             // alias: Qa dead after qkv_k

  prep_k<<<10240, 256, 0, stream>>>(queries, keys, values, Qa, Ka, Va,
                                    Wq, Wk, Wv, Wo, Wtq, Wtk, Wtv, Wto);
  qkv_k<<<768, 256, 0, stream>>>(Qa, Ka, Va, Wtq, Wtk, Wtv,
                                 qlnw, qlnb, klnw, klnb, Qn, Kn, Vb);
  flash_k<<<1024, 256, 0, stream>>>(Qn, Kn, Vb, Ob);
  gemmo_k<<<512, 256, 0, stream>>>(Ob, Wto, bo, out);
}